// Round 4
// baseline (21.327 us; speedup 1.0000x reference)
//
#include <hip/hip_runtime.h>

#define IN_DIM 10
#define OUT_DIM 3
#define BLOCK 256
#define MAX_BLOCKS 2048   // 256 CU x 8 blocks/CU

__device__ __forceinline__ float rfl(float v) {
    return __int_as_float(__builtin_amdgcn_readfirstlane(__float_as_int(v)));
}

// Persistent grid-stride kernel. Each thread owns 2 consecutive rows per
// iteration (80 B = 5 aligned float4 loads, 3 aligned float2 stores).
// proj = M^-1 @ W is wave-uniform -> pinned to SGPRs via readfirstlane.
__global__ __launch_bounds__(BLOCK, 8) void simnet_persist(
    const float* __restrict__ x,
    const float* __restrict__ W,
    const float* __restrict__ M,
    float* __restrict__ out,
    int npairs,
    long long batch)
{
    // ---- wave-uniform: inv(M) via adjugate, proj = inv @ W ----
    const float a = M[0], b = M[1], c = M[2];
    const float d = M[3], e = M[4], f_ = M[5];
    const float g = M[6], h = M[7], i_ = M[8];
    const float A =  (e * i_ - f_ * h);
    const float B = -(d * i_ - f_ * g);
    const float C =  (d * h  - e  * g);
    const float det = a * A + b * B + c * C;
    float inv[3][3];
    // torch.isclose(det, 0, rtol=1e-5, atol=1e-8) -> |det| <= 1e-8
    if (fabsf(det) <= 1e-8f) {
        const float qn = __builtin_nanf("");
        #pragma unroll
        for (int o = 0; o < 3; ++o)
            #pragma unroll
            for (int k = 0; k < 3; ++k) inv[o][k] = qn;
    } else {
        const float r = 1.0f / det;
        inv[0][0] = A * r;
        inv[0][1] = (c * h  - b * i_) * r;
        inv[0][2] = (b * f_ - c * e ) * r;
        inv[1][0] = B * r;
        inv[1][1] = (a * i_ - c * g ) * r;
        inv[1][2] = (c * d  - a * f_) * r;
        inv[2][0] = C * r;
        inv[2][1] = (b * g  - a * h ) * r;
        inv[2][2] = (a * e  - b * d ) * r;
    }
    // pj into SGPRs (uniform across the wave): frees ~30 VGPRs
    float pj[OUT_DIM][IN_DIM];
    #pragma unroll
    for (int o = 0; o < OUT_DIM; ++o)
        #pragma unroll
        for (int j = 0; j < IN_DIM; ++j)
            pj[o][j] = rfl(inv[o][0] * W[0 * IN_DIM + j]
                         + inv[o][1] * W[1 * IN_DIM + j]
                         + inv[o][2] * W[2 * IN_DIM + j]);

    const int tid    = blockIdx.x * BLOCK + threadIdx.x;
    const int stride = gridDim.x * BLOCK;

    #pragma unroll 1
    for (int p = tid; p < npairs; p += stride) {
        const float4* xv = reinterpret_cast<const float4*>(x) + 5 * (long long)p;
        const float4 v0 = xv[0];
        const float4 v1 = xv[1];
        const float4 v2 = xv[2];
        const float4 v3 = xv[3];
        const float4 v4 = xv[4];

        // rows: r0 = v0.xyzw v1.xyzw v2.xy ; r1 = v2.zw v3.xyzw v4.xyzw
        const float r0j[IN_DIM] = { v0.x, v0.y, v0.z, v0.w,
                                    v1.x, v1.y, v1.z, v1.w,
                                    v2.x, v2.y };
        const float r1j[IN_DIM] = { v2.z, v2.w,
                                    v3.x, v3.y, v3.z, v3.w,
                                    v4.x, v4.y, v4.z, v4.w };
        float y0[OUT_DIM], y1[OUT_DIM];
        #pragma unroll
        for (int o = 0; o < OUT_DIM; ++o) {
            float s0 = r0j[0] * pj[o][0];
            float s1 = r1j[0] * pj[o][0];
            #pragma unroll
            for (int j = 1; j < IN_DIM; ++j) {
                s0 = fmaf(r0j[j], pj[o][j], s0);
                s1 = fmaf(r1j[j], pj[o][j], s1);
            }
            y0[o] = s0;
            y1[o] = s1;
        }

        float2* o2 = reinterpret_cast<float2*>(out) + 3 * (long long)p;
        o2[0] = make_float2(y0[0], y0[1]);
        o2[1] = make_float2(y0[2], y1[0]);
        o2[2] = make_float2(y1[1], y1[2]);
    }

    // possible odd final row (not taken at batch = 2e6)
    if ((batch & 1LL) && tid == 0) {
        const long long row = batch - 1;
        const float* xr = x + row * IN_DIM;
        #pragma unroll
        for (int o = 0; o < OUT_DIM; ++o) {
            float s = 0.f;
            #pragma unroll
            for (int j = 0; j < IN_DIM; ++j) s = fmaf(xr[j], pj[o][j], s);
            out[row * OUT_DIM + o] = s;
        }
    }
}

extern "C" void kernel_launch(void* const* d_in, const int* in_sizes, int n_in,
                              void* d_out, int out_size, void* d_ws, size_t ws_size,
                              hipStream_t stream) {
    const float* x = (const float*)d_in[0];
    const float* W = (const float*)d_in[1];
    const float* M = (const float*)d_in[2];
    float* out = (float*)d_out;
    const long long batch = (long long)in_sizes[0] / IN_DIM;
    const int npairs = (int)(batch >> 1);
    int grid = (npairs + BLOCK - 1) / BLOCK;
    if (grid > MAX_BLOCKS) grid = MAX_BLOCKS;
    if (grid < 1) grid = 1;
    simnet_persist<<<grid, BLOCK, 0, stream>>>(x, W, M, out, npairs, batch);
}

// Round 5
// 21.106 us; speedup vs baseline: 1.0104x; 1.0104x over previous
//
#include <hip/hip_runtime.h>

#define IN_DIM 10
#define OUT_DIM 3
#define BLOCK 256

// One-shot kernel: each thread owns 4 consecutive rows.
//   in : 40 floats = 10 aligned float4 loads (160 B, offset 160*g)
//   out: 12 floats =  3 aligned float4 stores (48 B,  offset  48*g)
// No LDS, no barriers, no loops. All x loads issued before proj math so the
// wave-uniform inv(M)@W computation overlaps global-load latency.
__global__ __launch_bounds__(BLOCK) void simnet_x4(
    const float* __restrict__ x,
    const float* __restrict__ W,
    const float* __restrict__ M,
    float* __restrict__ out,
    long long batch)
{
    const long long g = (long long)blockIdx.x * BLOCK + threadIdx.x;
    const long long row0 = g * 4;
    if (row0 >= batch) return;

    const bool full = (row0 + 4 <= batch);

    // ---- issue x loads first (fast path) ----
    const float4* xv = reinterpret_cast<const float4*>(x) + 10 * g;
    float4 u0, u1, u2, u3, u4, u5, u6, u7, u8, u9;
    if (full) {
        u0 = xv[0]; u1 = xv[1]; u2 = xv[2]; u3 = xv[3]; u4 = xv[4];
        u5 = xv[5]; u6 = xv[6]; u7 = xv[7]; u8 = xv[8]; u9 = xv[9];
    }

    // ---- wave-uniform: inv(M) via adjugate, proj = inv @ W ----
    const float a = M[0], b = M[1], c = M[2];
    const float d = M[3], e = M[4], f_ = M[5];
    const float g_ = M[6], h = M[7], i_ = M[8];
    const float A =  (e * i_ - f_ * h);
    const float B = -(d * i_ - f_ * g_);
    const float C =  (d * h  - e  * g_);
    const float det = a * A + b * B + c * C;
    float inv[3][3];
    // torch.isclose(det, 0, rtol=1e-5, atol=1e-8) -> |det| <= 1e-8
    if (fabsf(det) <= 1e-8f) {
        const float qn = __builtin_nanf("");
        #pragma unroll
        for (int o = 0; o < 3; ++o)
            #pragma unroll
            for (int k = 0; k < 3; ++k) inv[o][k] = qn;
    } else {
        const float r = 1.0f / det;
        inv[0][0] = A * r;
        inv[0][1] = (c * h  - b * i_) * r;
        inv[0][2] = (b * f_ - c * e ) * r;
        inv[1][0] = B * r;
        inv[1][1] = (a * i_ - c * g_) * r;
        inv[1][2] = (c * d  - a * f_) * r;
        inv[2][0] = C * r;
        inv[2][1] = (b * g_ - a * h ) * r;
        inv[2][2] = (a * e  - b * d ) * r;
    }
    float pj[OUT_DIM][IN_DIM];
    #pragma unroll
    for (int o = 0; o < OUT_DIM; ++o)
        #pragma unroll
        for (int j = 0; j < IN_DIM; ++j)
            pj[o][j] = inv[o][0] * W[0 * IN_DIM + j]
                     + inv[o][1] * W[1 * IN_DIM + j]
                     + inv[o][2] * W[2 * IN_DIM + j];

    if (full) {
        // rows from the 10 float4s (40 consecutive floats)
        const float r0j[IN_DIM] = { u0.x,u0.y,u0.z,u0.w, u1.x,u1.y,u1.z,u1.w, u2.x,u2.y };
        const float r1j[IN_DIM] = { u2.z,u2.w, u3.x,u3.y,u3.z,u3.w, u4.x,u4.y,u4.z,u4.w };
        const float r2j[IN_DIM] = { u5.x,u5.y,u5.z,u5.w, u6.x,u6.y,u6.z,u6.w, u7.x,u7.y };
        const float r3j[IN_DIM] = { u7.z,u7.w, u8.x,u8.y,u8.z,u8.w, u9.x,u9.y,u9.z,u9.w };

        float y0[OUT_DIM], y1[OUT_DIM], y2[OUT_DIM], y3[OUT_DIM];
        #pragma unroll
        for (int o = 0; o < OUT_DIM; ++o) {
            float s0 = r0j[0] * pj[o][0];
            float s1 = r1j[0] * pj[o][0];
            float s2 = r2j[0] * pj[o][0];
            float s3 = r3j[0] * pj[o][0];
            #pragma unroll
            for (int j = 1; j < IN_DIM; ++j) {
                s0 = fmaf(r0j[j], pj[o][j], s0);
                s1 = fmaf(r1j[j], pj[o][j], s1);
                s2 = fmaf(r2j[j], pj[o][j], s2);
                s3 = fmaf(r3j[j], pj[o][j], s3);
            }
            y0[o] = s0; y1[o] = s1; y2[o] = s2; y3[o] = s3;
        }

        float4* o4 = reinterpret_cast<float4*>(out) + 3 * g;
        o4[0] = make_float4(y0[0], y0[1], y0[2], y1[0]);
        o4[1] = make_float4(y1[1], y1[2], y2[0], y2[1]);
        o4[2] = make_float4(y2[2], y3[0], y3[1], y3[2]);
    } else {
        // partial group (not taken when batch % 4 == 0): scalar fallback
        for (long long row = row0; row < batch; ++row) {
            const float* xr = x + row * IN_DIM;
            float xj[IN_DIM];
            #pragma unroll
            for (int j = 0; j < IN_DIM; ++j) xj[j] = xr[j];
            #pragma unroll
            for (int o = 0; o < OUT_DIM; ++o) {
                float s = 0.f;
                #pragma unroll
                for (int j = 0; j < IN_DIM; ++j) s = fmaf(xj[j], pj[o][j], s);
                out[row * OUT_DIM + o] = s;
            }
        }
    }
}

extern "C" void kernel_launch(void* const* d_in, const int* in_sizes, int n_in,
                              void* d_out, int out_size, void* d_ws, size_t ws_size,
                              hipStream_t stream) {
    const float* x = (const float*)d_in[0];
    const float* W = (const float*)d_in[1];
    const float* M = (const float*)d_in[2];
    float* out = (float*)d_out;
    const long long batch = (long long)in_sizes[0] / IN_DIM;
    const long long ngroups = (batch + 3) / 4;            // 500000 at 2e6
    const int grid = (int)((ngroups + BLOCK - 1) / BLOCK); // 1954
    simnet_x4<<<grid, BLOCK, 0, stream>>>(x, W, M, out, batch);
}

// Round 6
// 21.104 us; speedup vs baseline: 1.0105x; 1.0001x over previous
//
#include <hip/hip_runtime.h>

#define IN_DIM 10
#define OUT_DIM 3
#define BLOCK 256
#define ITERS_TARGET 4
#define MAX_GRID 2048

__device__ __forceinline__ float rfl(float v) {
    return __int_as_float(__builtin_amdgcn_readfirstlane(__float_as_int(v)));
}

// Persistent software-pipelined kernel. Each iteration handles 2 consecutive
// rows/thread (80 B = 5 aligned float4 loads, 3 aligned float2 stores).
// Next iteration's loads are issued BEFORE current iteration's compute+store.
// Grid sized so all blocks are co-resident (no drain taper).
__global__ __launch_bounds__(BLOCK, 4) void simnet_pipe(
    const float* __restrict__ x,
    const float* __restrict__ W,
    const float* __restrict__ M,
    float* __restrict__ out,
    int npairs,
    long long batch)
{
    // ---- wave-uniform: inv(M) via adjugate, proj = inv @ W, into SGPRs ----
    const float a = M[0], b = M[1], c = M[2];
    const float d = M[3], e = M[4], f_ = M[5];
    const float g_ = M[6], h = M[7], i_ = M[8];
    const float A =  (e * i_ - f_ * h);
    const float B = -(d * i_ - f_ * g_);
    const float C =  (d * h  - e  * g_);
    const float det = a * A + b * B + c * C;
    float inv[3][3];
    // torch.isclose(det, 0, rtol=1e-5, atol=1e-8) -> |det| <= 1e-8
    if (fabsf(det) <= 1e-8f) {
        const float qn = __builtin_nanf("");
        #pragma unroll
        for (int o = 0; o < 3; ++o)
            #pragma unroll
            for (int k = 0; k < 3; ++k) inv[o][k] = qn;
    } else {
        const float r = 1.0f / det;
        inv[0][0] = A * r;
        inv[0][1] = (c * h  - b * i_) * r;
        inv[0][2] = (b * f_ - c * e ) * r;
        inv[1][0] = B * r;
        inv[1][1] = (a * i_ - c * g_) * r;
        inv[1][2] = (c * d  - a * f_) * r;
        inv[2][0] = C * r;
        inv[2][1] = (b * g_ - a * h ) * r;
        inv[2][2] = (a * e  - b * d ) * r;
    }
    float pj[OUT_DIM][IN_DIM];
    #pragma unroll
    for (int o = 0; o < OUT_DIM; ++o)
        #pragma unroll
        for (int j = 0; j < IN_DIM; ++j)
            pj[o][j] = rfl(inv[o][0] * W[0 * IN_DIM + j]
                         + inv[o][1] * W[1 * IN_DIM + j]
                         + inv[o][2] * W[2 * IN_DIM + j]);

    const int tid    = blockIdx.x * BLOCK + threadIdx.x;
    const int stride = gridDim.x * BLOCK;

    int p = tid;
    bool have = (p < npairs);
    float4 b0, b1, b2, b3, b4;
    if (have) {
        const float4* xv = reinterpret_cast<const float4*>(x) + 5LL * p;
        b0 = xv[0]; b1 = xv[1]; b2 = xv[2]; b3 = xv[3]; b4 = xv[4];
    }

    #pragma unroll 1
    while (have) {
        // ---- prefetch next pair before touching current data ----
        const int pn = p + stride;
        const bool haven = (pn < npairs);
        float4 n0 = {}, n1 = {}, n2 = {}, n3 = {}, n4 = {};
        if (haven) {
            const float4* xv = reinterpret_cast<const float4*>(x) + 5LL * pn;
            n0 = xv[0]; n1 = xv[1]; n2 = xv[2]; n3 = xv[3]; n4 = xv[4];
        }

        // ---- compute current pair ----
        // r0 = b0.xyzw b1.xyzw b2.xy ; r1 = b2.zw b3.xyzw b4.xyzw
        const float r0j[IN_DIM] = { b0.x, b0.y, b0.z, b0.w,
                                    b1.x, b1.y, b1.z, b1.w,
                                    b2.x, b2.y };
        const float r1j[IN_DIM] = { b2.z, b2.w,
                                    b3.x, b3.y, b3.z, b3.w,
                                    b4.x, b4.y, b4.z, b4.w };
        float y0[OUT_DIM], y1[OUT_DIM];
        #pragma unroll
        for (int o = 0; o < OUT_DIM; ++o) {
            float s0 = r0j[0] * pj[o][0];
            float s1 = r1j[0] * pj[o][0];
            #pragma unroll
            for (int j = 1; j < IN_DIM; ++j) {
                s0 = fmaf(r0j[j], pj[o][j], s0);
                s1 = fmaf(r1j[j], pj[o][j], s1);
            }
            y0[o] = s0;
            y1[o] = s1;
        }

        float2* o2 = reinterpret_cast<float2*>(out) + 3LL * p;
        o2[0] = make_float2(y0[0], y0[1]);
        o2[1] = make_float2(y0[2], y1[0]);
        o2[2] = make_float2(y1[1], y1[2]);

        // ---- rotate pipeline ----
        p = pn; have = haven;
        b0 = n0; b1 = n1; b2 = n2; b3 = n3; b4 = n4;
    }

    // possible odd final row (not taken at batch = 2e6)
    if ((batch & 1LL) && tid == 0) {
        const long long row = batch - 1;
        const float* xr = x + row * IN_DIM;
        #pragma unroll
        for (int o = 0; o < OUT_DIM; ++o) {
            float s = 0.f;
            #pragma unroll
            for (int j = 0; j < IN_DIM; ++j) s = fmaf(xr[j], pj[o][j], s);
            out[row * OUT_DIM + o] = s;
        }
    }
}

extern "C" void kernel_launch(void* const* d_in, const int* in_sizes, int n_in,
                              void* d_out, int out_size, void* d_ws, size_t ws_size,
                              hipStream_t stream) {
    const float* x = (const float*)d_in[0];
    const float* W = (const float*)d_in[1];
    const float* M = (const float*)d_in[2];
    float* out = (float*)d_out;
    const long long batch = (long long)in_sizes[0] / IN_DIM;
    const int npairs = (int)(batch >> 1);
    int grid = (npairs + BLOCK * ITERS_TARGET - 1) / (BLOCK * ITERS_TARGET); // 977 @ 2e6
    if (grid > MAX_GRID) grid = MAX_GRID;
    if (grid < 1) grid = 1;
    simnet_pipe<<<grid, BLOCK, 0, stream>>>(x, W, M, out, npairs, batch);
}

// Round 7
// 20.736 us; speedup vs baseline: 1.0285x; 1.0178x over previous
//
#include <hip/hip_runtime.h>

#define IN_DIM 10
#define OUT_DIM 3
#define BLOCK 128   // 2 waves/block: fine-grained one-shot blocks, ~30/CU -> ~3% tail taper

typedef float f32x2 __attribute__((ext_vector_type(2)));

// One-shot kernel: each thread owns 2 consecutive rows (80 B = 5 aligned
// float4 loads), writes 6 floats as 3 aligned NON-TEMPORAL float2 stores.
// No LDS, no barriers. x loads issued before the wave-uniform proj math so
// inv(M)@W overlaps global-load latency.
__global__ __launch_bounds__(BLOCK) void simnet_nt(
    const float* __restrict__ x,
    const float* __restrict__ W,
    const float* __restrict__ M,
    float* __restrict__ out,
    int npairs,
    long long batch)
{
    const int p = blockIdx.x * BLOCK + threadIdx.x;
    const bool have = (p < npairs);

    // ---- issue x loads first ----
    float4 v0, v1, v2, v3, v4;
    if (have) {
        const float4* xv = reinterpret_cast<const float4*>(x) + 5LL * p;
        v0 = xv[0]; v1 = xv[1]; v2 = xv[2]; v3 = xv[3]; v4 = xv[4];
    }

    // ---- wave-uniform: inv(M) via adjugate, proj = inv @ W ----
    const float a = M[0], b = M[1], c = M[2];
    const float d = M[3], e = M[4], f_ = M[5];
    const float g_ = M[6], h = M[7], i_ = M[8];
    const float A =  (e * i_ - f_ * h);
    const float B = -(d * i_ - f_ * g_);
    const float C =  (d * h  - e  * g_);
    const float det = a * A + b * B + c * C;
    float inv[3][3];
    // torch.isclose(det, 0, rtol=1e-5, atol=1e-8) -> |det| <= 1e-8
    if (fabsf(det) <= 1e-8f) {
        const float qn = __builtin_nanf("");
        #pragma unroll
        for (int o = 0; o < 3; ++o)
            #pragma unroll
            for (int k = 0; k < 3; ++k) inv[o][k] = qn;
    } else {
        const float r = 1.0f / det;
        inv[0][0] = A * r;
        inv[0][1] = (c * h  - b * i_) * r;
        inv[0][2] = (b * f_ - c * e ) * r;
        inv[1][0] = B * r;
        inv[1][1] = (a * i_ - c * g_) * r;
        inv[1][2] = (c * d  - a * f_) * r;
        inv[2][0] = C * r;
        inv[2][1] = (b * g_ - a * h ) * r;
        inv[2][2] = (a * e  - b * d ) * r;
    }
    float pj[OUT_DIM][IN_DIM];
    #pragma unroll
    for (int o = 0; o < OUT_DIM; ++o)
        #pragma unroll
        for (int j = 0; j < IN_DIM; ++j)
            pj[o][j] = inv[o][0] * W[0 * IN_DIM + j]
                     + inv[o][1] * W[1 * IN_DIM + j]
                     + inv[o][2] * W[2 * IN_DIM + j];

    if (have) {
        // rows: r0 = v0.xyzw v1.xyzw v2.xy ; r1 = v2.zw v3.xyzw v4.xyzw
        const float r0j[IN_DIM] = { v0.x, v0.y, v0.z, v0.w,
                                    v1.x, v1.y, v1.z, v1.w,
                                    v2.x, v2.y };
        const float r1j[IN_DIM] = { v2.z, v2.w,
                                    v3.x, v3.y, v3.z, v3.w,
                                    v4.x, v4.y, v4.z, v4.w };
        float y0[OUT_DIM], y1[OUT_DIM];
        #pragma unroll
        for (int o = 0; o < OUT_DIM; ++o) {
            float s0 = r0j[0] * pj[o][0];
            float s1 = r1j[0] * pj[o][0];
            #pragma unroll
            for (int j = 1; j < IN_DIM; ++j) {
                s0 = fmaf(r0j[j], pj[o][j], s0);
                s1 = fmaf(r1j[j], pj[o][j], s1);
            }
            y0[o] = s0;
            y1[o] = s1;
        }

        // ---- 3 aligned non-temporal float2 stores (write-once stream) ----
        f32x2* o2 = reinterpret_cast<f32x2*>(out) + 3LL * p;
        f32x2 w0; w0.x = y0[0]; w0.y = y0[1];
        f32x2 w1; w1.x = y0[2]; w1.y = y1[0];
        f32x2 w2; w2.x = y1[1]; w2.y = y1[2];
        __builtin_nontemporal_store(w0, o2 + 0);
        __builtin_nontemporal_store(w1, o2 + 1);
        __builtin_nontemporal_store(w2, o2 + 2);
    }

    // possible odd final row (not taken at batch = 2e6)
    if ((batch & 1LL) && p == 0) {
        const long long row = batch - 1;
        const float* xr = x + row * IN_DIM;
        #pragma unroll
        for (int o = 0; o < OUT_DIM; ++o) {
            float s = 0.f;
            #pragma unroll
            for (int j = 0; j < IN_DIM; ++j) s = fmaf(xr[j], pj[o][j], s);
            out[row * OUT_DIM + o] = s;
        }
    }
}

extern "C" void kernel_launch(void* const* d_in, const int* in_sizes, int n_in,
                              void* d_out, int out_size, void* d_ws, size_t ws_size,
                              hipStream_t stream) {
    const float* x = (const float*)d_in[0];
    const float* W = (const float*)d_in[1];
    const float* M = (const float*)d_in[2];
    float* out = (float*)d_out;
    const long long batch = (long long)in_sizes[0] / IN_DIM;
    const int npairs = (int)(batch >> 1);
    const int grid = (npairs + BLOCK - 1) / BLOCK;   // 7813 @ 2e6
    simnet_nt<<<grid, BLOCK, 0, stream>>>(x, W, M, out, npairs, batch);
}